// Round 2
// baseline (2058.084 us; speedup 1.0000x reference)
//
#include <hip/hip_runtime.h>
#include <stdint.h>

#define Bb 8
#define Ss 4096
#define Dd 1024
#define Mm (Bb*Ss)      // 32768 rows
#define Kk 1024

typedef _Float16 half8 __attribute__((ext_vector_type(8)));
typedef _Float16 half4v __attribute__((ext_vector_type(4)));
typedef float f32x4 __attribute__((ext_vector_type(4)));

#define LO_SCALE 2048.0f
#define INV_LO_SCALE (1.0f/2048.0f)

__device__ __forceinline__ void gld_lds16(const void* g, void* l) {
  __builtin_amdgcn_global_load_lds(
      (const __attribute__((address_space(1))) unsigned int*)g,
      (__attribute__((address_space(3))) unsigned int*)l, 16, 0, 0);
}

// ---------------- elementwise fp32 -> f16 hi/lo split (lo pre-scaled) --------
__global__ void split_kernel(const float* __restrict__ src,
                             _Float16* __restrict__ hi,
                             _Float16* __restrict__ lo, int n4) {
  int i = blockIdx.x * 256 + threadIdx.x;
  if (i >= n4) return;
  float4 v = ((const float4*)src)[i];
  _Float16 h0 = (_Float16)v.x, h1 = (_Float16)v.y, h2 = (_Float16)v.z, h3 = (_Float16)v.w;
  _Float16 l0 = (_Float16)((v.x - (float)h0) * LO_SCALE);
  _Float16 l1 = (_Float16)((v.y - (float)h1) * LO_SCALE);
  _Float16 l2 = (_Float16)((v.z - (float)h2) * LO_SCALE);
  _Float16 l3 = (_Float16)((v.w - (float)h3) * LO_SCALE);
  ((half4v*)hi)[i] = (half4v){h0, h1, h2, h3};
  ((half4v*)lo)[i] = (half4v){l0, l1, l2, l3};
}

// ---------------- X split (wave/row) + a_u = u.x, a_v = v.x ------------------
__global__ void split_x(const float* __restrict__ X, const float* __restrict__ u,
                        const float* __restrict__ v,
                        _Float16* __restrict__ Xh, _Float16* __restrict__ Xl,
                        float* __restrict__ a_u, float* __restrict__ a_v) {
  const int s = blockIdx.x * 4 + (threadIdx.x >> 6);
  const int lane = threadIdx.x & 63;
  float au = 0.f, av = 0.f;
#pragma unroll
  for (int c = 0; c < 4; ++c) {
    const int e = c * 256 + lane * 4;
    float4 xv = *(const float4*)&X[(size_t)s * Dd + e];
    float4 uv = *(const float4*)&u[e];
    float4 vv = *(const float4*)&v[e];
    _Float16 h0 = (_Float16)xv.x, h1 = (_Float16)xv.y, h2 = (_Float16)xv.z, h3 = (_Float16)xv.w;
    _Float16 l0 = (_Float16)((xv.x - (float)h0) * LO_SCALE);
    _Float16 l1 = (_Float16)((xv.y - (float)h1) * LO_SCALE);
    _Float16 l2 = (_Float16)((xv.z - (float)h2) * LO_SCALE);
    _Float16 l3 = (_Float16)((xv.w - (float)h3) * LO_SCALE);
    *(half4v*)&Xh[(size_t)s * Dd + e] = (half4v){h0, h1, h2, h3};
    *(half4v*)&Xl[(size_t)s * Dd + e] = (half4v){l0, l1, l2, l3};
    au += uv.x * xv.x + uv.y * xv.y + uv.z * xv.z + uv.w * xv.w;
    av += vv.x * xv.x + vv.y * xv.y + vv.z * xv.z + vv.w * xv.w;
  }
#pragma unroll
  for (int off = 32; off > 0; off >>= 1) {
    au += __shfl_xor(au, off);
    av += __shfl_xor(av, off);
  }
  if (lane == 0) { a_u[s] = au; a_v[s] = av; }
}

// ---------------- G = Wq^T * Wk (fp32 vector GEMM, 64x64 tiles) --------------
__global__ __launch_bounds__(256)
void gemm_g(const float* __restrict__ Wq, const float* __restrict__ Wk,
            float* __restrict__ G) {
  __shared__ float As[16][64];
  __shared__ float Bs[16][64];
  const int t = threadIdx.x;
  const int m0 = blockIdx.y * 64, n0 = blockIdx.x * 64;
  float acc[4][4];
#pragma unroll
  for (int a = 0; a < 4; ++a)
#pragma unroll
    for (int b = 0; b < 4; ++b) acc[a][b] = 0.f;
  for (int kc = 0; kc < 64; ++kc) {
    const int k0 = kc * 16;
#pragma unroll
    for (int l = 0; l < 4; ++l) {
      const int idx = l * 256 + t;
      const int kk = idx >> 6, mm = idx & 63;
      As[kk][mm] = Wq[(size_t)(k0 + kk) * Dd + m0 + mm];
      Bs[kk][mm] = Wk[(size_t)(k0 + kk) * Dd + n0 + mm];
    }
    __syncthreads();
    const int tm = (t & 15) * 4, tn = (t >> 4) * 4;
#pragma unroll
    for (int k = 0; k < 16; ++k) {
      float4 a4 = *(const float4*)&As[k][tm];
      float4 b4 = *(const float4*)&Bs[k][tn];
      const float aa[4] = {a4.x, a4.y, a4.z, a4.w};
      const float bb[4] = {b4.x, b4.y, b4.z, b4.w};
#pragma unroll
      for (int a = 0; a < 4; ++a)
#pragma unroll
        for (int b = 0; b < 4; ++b) acc[a][b] += aa[a] * bb[b];
    }
    __syncthreads();
  }
  const int tm = (t & 15) * 4, tn = (t >> 4) * 4;
#pragma unroll
  for (int a = 0; a < 4; ++a)
#pragma unroll
    for (int b = 0; b < 4; ++b)
      G[(size_t)(m0 + tm + a) * Dd + n0 + tn + b] = acc[a][b];
}

// ---------------- u[d] = sum_e bq[e] Wk[e,d]; v[d] = sum_e bk[e] Wq[e,d] -----
__global__ void uv_pass(const float* __restrict__ Wq, const float* __restrict__ Wk,
                        const float* __restrict__ bq, const float* __restrict__ bk,
                        float* __restrict__ u, float* __restrict__ v) {
  const int d = blockIdx.x * 256 + threadIdx.x;
  const int which = blockIdx.y;  // 0 -> u, 1 -> v
  const float* W = which ? Wq : Wk;
  const float* bb = which ? bk : bq;
  float acc = 0.f;
#pragma unroll 4
  for (int e = 0; e < Dd; ++e) acc += bb[e] * W[(size_t)e * Dd + d];
  if (which) v[d] = acc; else u[d] = acc;
}

__global__ void c_pass(const float* __restrict__ bq, const float* __restrict__ bk,
                       float* __restrict__ c) {
  const int lane = threadIdx.x;
  float a = 0.f;
#pragma unroll
  for (int i = 0; i < 16; ++i) a += bq[lane * 16 + i] * bk[lane * 16 + i];
#pragma unroll
  for (int off = 32; off > 0; off >>= 1) a += __shfl_xor(a, off);
  if (lane == 0) *c = a;
}

// ---------------- precise split GEMM: Y = X * G^T  (N=1024) ------------------
// swizzled LDS: LDS[R][slot] holds global col-group slot ^ ((R>>2)&3)
__global__ __launch_bounds__(256, 4)
void gemm_y(const _Float16* __restrict__ Ah, const _Float16* __restrict__ Al,
            const _Float16* __restrict__ Bh, const _Float16* __restrict__ Bl,
            float* __restrict__ Y) {
  __shared__ __align__(16) _Float16 AsH[128 * 32];
  __shared__ __align__(16) _Float16 AsL[128 * 32];
  __shared__ __align__(16) _Float16 BsH[128 * 32];
  __shared__ __align__(16) _Float16 BsL[128 * 32];
  const int tid = threadIdx.x;
  const int wave = tid >> 6, lane = tid & 63;
  const int m0 = blockIdx.y * 128, n0 = blockIdx.x * 128;
  const int wm = (wave >> 1) * 64, wn = (wave & 1) * 64;

  f32x4 accH[4][4], accX[4][4];
#pragma unroll
  for (int i = 0; i < 4; ++i)
#pragma unroll
    for (int j = 0; j < 4; ++j) {
      accH[i][j] = (f32x4){0.f, 0.f, 0.f, 0.f};
      accX[i][j] = (f32x4){0.f, 0.f, 0.f, 0.f};
    }
  const int srow = lane >> 2, c8 = lane & 3;

  for (int kt = 0; kt < Kk / 32; ++kt) {
    const int k0 = kt * 32;
#pragma unroll
    for (int it = 0; it < 2; ++it) {
      const int R = wave * 32 + it * 16 + srow;
      const int sg = c8 ^ ((R >> 2) & 3);
      const int ldsoff = (wave * 32 + it * 16) * 32;
      const size_t ga = (size_t)(m0 + R) * Kk + k0 + sg * 8;
      const size_t gb = (size_t)(n0 + R) * Kk + k0 + sg * 8;
      gld_lds16(Ah + ga, &AsH[ldsoff]);
      gld_lds16(Al + ga, &AsL[ldsoff]);
      gld_lds16(Bh + gb, &BsH[ldsoff]);
      gld_lds16(Bl + gb, &BsL[ldsoff]);
    }
    __syncthreads();
    const int fr = lane & 15, g = lane >> 4;
    half8 bh[4], bl[4];
#pragma unroll
    for (int j = 0; j < 4; ++j) {
      const int R = wn + 16 * j + fr;
      const int slot = g ^ ((R >> 2) & 3);
      bh[j] = *(const half8*)&BsH[R * 32 + slot * 8];
      bl[j] = *(const half8*)&BsL[R * 32 + slot * 8];
    }
#pragma unroll
    for (int i = 0; i < 4; ++i) {
      const int R = wm + 16 * i + fr;
      const int slot = g ^ ((R >> 2) & 3);
      half8 ah = *(const half8*)&AsH[R * 32 + slot * 8];
      half8 al = *(const half8*)&AsL[R * 32 + slot * 8];
#pragma unroll
      for (int j = 0; j < 4; ++j) {
        accH[i][j] = __builtin_amdgcn_mfma_f32_16x16x32_f16(ah, bh[j], accH[i][j], 0, 0, 0);
        accX[i][j] = __builtin_amdgcn_mfma_f32_16x16x32_f16(ah, bl[j], accX[i][j], 0, 0, 0);
        accX[i][j] = __builtin_amdgcn_mfma_f32_16x16x32_f16(al, bh[j], accX[i][j], 0, 0, 0);
      }
    }
    __syncthreads();
  }
  const int quad = lane >> 4;
#pragma unroll
  for (int j = 0; j < 4; ++j) {
    const int n = n0 + wn + 16 * j + (lane & 15);
#pragma unroll
    for (int i = 0; i < 4; ++i) {
      const int row0 = m0 + wm + 16 * i + quad * 4;
#pragma unroll
      for (int r = 0; r < 4; ++r)
        Y[(size_t)(row0 + r) * Dd + n] = accH[i][j][r] + accX[i][j][r] * INV_LO_SCALE;
    }
  }
}

// ---------------- single-pass hh GEMM for norms (N=2048, no QK write) --------
__global__ __launch_bounds__(256, 4)
void gemm_norm(const _Float16* __restrict__ Ah, const _Float16* __restrict__ Bh,
               const float* __restrict__ bq, const float* __restrict__ bk,
               float* __restrict__ partials) {
  __shared__ __align__(16) _Float16 AsH[128 * 32];
  __shared__ __align__(16) _Float16 BsH[128 * 32];
  const int tid = threadIdx.x;
  const int wave = tid >> 6, lane = tid & 63;
  const int m0 = blockIdx.y * 128, n0 = blockIdx.x * 128;
  const int wm = (wave >> 1) * 64, wn = (wave & 1) * 64;

  f32x4 acc[4][4];
#pragma unroll
  for (int i = 0; i < 4; ++i)
#pragma unroll
    for (int j = 0; j < 4; ++j) acc[i][j] = (f32x4){0.f, 0.f, 0.f, 0.f};

  const int srow = lane >> 2, c8 = lane & 3;
  for (int kt = 0; kt < Kk / 32; ++kt) {
    const int k0 = kt * 32;
#pragma unroll
    for (int it = 0; it < 2; ++it) {
      const int R = wave * 32 + it * 16 + srow;
      const int sg = c8 ^ ((R >> 2) & 3);
      const int ldsoff = (wave * 32 + it * 16) * 32;
      gld_lds16(Ah + (size_t)(m0 + R) * Kk + k0 + sg * 8, &AsH[ldsoff]);
      gld_lds16(Bh + (size_t)(n0 + R) * Kk + k0 + sg * 8, &BsH[ldsoff]);
    }
    __syncthreads();
    const int fr = lane & 15, g = lane >> 4;
    half8 bh[4];
#pragma unroll
    for (int j = 0; j < 4; ++j) {
      const int R = wn + 16 * j + fr;
      const int slot = g ^ ((R >> 2) & 3);
      bh[j] = *(const half8*)&BsH[R * 32 + slot * 8];
    }
#pragma unroll
    for (int i = 0; i < 4; ++i) {
      const int R = wm + 16 * i + fr;
      const int slot = g ^ ((R >> 2) & 3);
      half8 ah = *(const half8*)&AsH[R * 32 + slot * 8];
#pragma unroll
      for (int j = 0; j < 4; ++j)
        acc[i][j] = __builtin_amdgcn_mfma_f32_16x16x32_f16(ah, bh[j], acc[i][j], 0, 0, 0);
    }
    __syncthreads();
  }
  // epilogue: per-row sum of (acc+bias)^2 over this wave's 64 cols
  const int quad = lane >> 4;
  float bias_j[4];
#pragma unroll
  for (int j = 0; j < 4; ++j) {
    const int n = n0 + wn + 16 * j + (lane & 15);
    bias_j[j] = (n < Dd) ? bq[n] : bk[n - Dd];
  }
  const int slot = blockIdx.x * 2 + (wave & 1);
#pragma unroll
  for (int i = 0; i < 4; ++i) {
#pragma unroll
    for (int r = 0; r < 4; ++r) {
      float vsum = 0.f;
#pragma unroll
      for (int j = 0; j < 4; ++j) {
        float q = acc[i][j][r] + bias_j[j];
        vsum += q * q;
      }
      vsum += __shfl_xor(vsum, 1);
      vsum += __shfl_xor(vsum, 2);
      vsum += __shfl_xor(vsum, 4);
      vsum += __shfl_xor(vsum, 8);
      if ((lane & 15) == 0)
        partials[(size_t)slot * Mm + (m0 + wm + 16 * i + quad * 4 + r)] = vsum;
    }
  }
}

// ---------------- cos / p / b (wave per row) ---------------------------------
__global__ void cos_pass(const float* __restrict__ X, const float* __restrict__ Y,
                         const float* __restrict__ P, const float* __restrict__ a_u,
                         const float* __restrict__ a_v, const float* __restrict__ cptr,
                         float* __restrict__ p_out, float* __restrict__ b_out) {
  const int s = blockIdx.x * 4 + (threadIdx.x >> 6);
  const int lane = threadIdx.x & 63;
  if ((s & (Ss - 1)) == 0) {
    if (lane == 0) { p_out[s] = 1.0f; b_out[s] = 1.0f; }
    return;
  }
  const float* xs = X + (size_t)s * Dd;
  const float* ym = Y + (size_t)(s - 1) * Dd;
  float d = 0.f;
#pragma unroll
  for (int c = 0; c < 4; ++c) {
    const int e = c * 256 + lane * 4;
    float4 xv = *(const float4*)&xs[e];
    float4 yv = *(const float4*)&ym[e];
    d += xv.x * yv.x + xv.y * yv.y + xv.z * yv.z + xv.w * yv.w;
  }
#pragma unroll
  for (int off = 32; off > 0; off >>= 1) d += __shfl_xor(d, off);

  float pn = 0.f;
  if (lane < 32) pn = P[(size_t)lane * Mm + ((lane < 16) ? s : (s - 1))];
  pn += __shfl_xor(pn, 1);
  pn += __shfl_xor(pn, 2);
  pn += __shfl_xor(pn, 4);
  pn += __shfl_xor(pn, 8);
  float nk2 = __shfl(pn, 16);
  if (lane == 0) {
    float nq2 = pn;
    float dot = d + a_u[s - 1] + a_v[s] + *cptr;
    float denom = fmaxf(sqrtf(nq2), 1e-8f) * fmaxf(sqrtf(nk2), 1e-8f);
    float cs = dot / denom;
    float p = 0.5f * (1.0f - cs);
    p_out[s] = p;
    b_out[s] = (p >= 0.5f) ? 1.0f : 0.0f;
  }
}

// ---------------- per-batch stable scan of flags -----------------------------
__global__ void scan_flags(const float* __restrict__ b_out,
                           int* __restrict__ sel, int* __restrict__ counts) {
  const int b = blockIdx.x;
  const int tid = threadIdx.x;
  const int lane = tid & 63;
  const int w = tid >> 6;
  __shared__ int wtot[4];
  int running = 0;
  for (int c = 0; c < Ss / 256; ++c) {
    const int i = c * 256 + tid;
    const bool f = b_out[b * Ss + i] != 0.0f;
    unsigned long long m = __ballot(f);
    int pre = __popcll(m & ((1ull << lane) - 1ull));
    if (lane == 0) wtot[w] = __popcll(m);
    __syncthreads();
    int woff = 0;
#pragma unroll
    for (int ww = 0; ww < 4; ++ww)
      if (ww < w) woff += wtot[ww];
    int tot = wtot[0] + wtot[1] + wtot[2] + wtot[3];
    if (f) sel[b * Ss + running + woff + pre] = i;
    running += tot;
    __syncthreads();
  }
  if (tid == 0) counts[b] = running;
}

// ---------------- gather selected rows / zero-fill ---------------------------
__global__ void write_out(const float* __restrict__ x, const int* __restrict__ sel,
                          const int* __restrict__ counts, float* __restrict__ out) {
  const int blk = blockIdx.x;
  const int b = blk >> 12;
  const int r = blk & (Ss - 1);
  const int tid = threadIdx.x;
  float4 v = {0.f, 0.f, 0.f, 0.f};
  if (r < counts[b]) {
    const int src = sel[b * Ss + r];
    v = *(const float4*)&x[((size_t)b * Ss + src) * Dd + tid * 4];
  }
  *(float4*)&out[(size_t)blk * Dd + tid * 4] = v;
}

extern "C" void kernel_launch(void* const* d_in, const int* in_sizes, int n_in,
                              void* d_out, int out_size, void* d_ws, size_t ws_size,
                              hipStream_t stream) {
  const float* x  = (const float*)d_in[0];
  const float* Wq = (const float*)d_in[1];
  const float* bq = (const float*)d_in[2];
  const float* Wk = (const float*)d_in[3];
  const float* bk = (const float*)d_in[4];
  float* out = (float*)d_out;

  uint8_t* w = (uint8_t*)d_ws;
  _Float16* Xh = (_Float16*)w;   w += (size_t)Mm * Kk * 2;   // 64 MB
  _Float16* Xl = (_Float16*)w;   w += (size_t)Mm * Kk * 2;   // 64 MB
  float*    Y  = (float*)w;      w += (size_t)Mm * Dd * 4;   // 128 MB
  float*    G  = (float*)w;      w += (size_t)Dd * Dd * 4;   // 4 MB
  _Float16* Gh = (_Float16*)w;   w += (size_t)Dd * Dd * 2;   // 2 MB
  _Float16* Gl = (_Float16*)w;   w += (size_t)Dd * Dd * 2;   // 2 MB
  _Float16* Wh = (_Float16*)w;   w += (size_t)2 * Dd * Dd * 2; // 4 MB
  _Float16* Wl = (_Float16*)w;   w += (size_t)2 * Dd * Dd * 2; // 4 MB
  float* partials = (float*)w;   w += (size_t)32 * Mm * 4;   // 4 MB
  float* a_u = (float*)w;        w += (size_t)Mm * 4;
  float* a_v = (float*)w;        w += (size_t)Mm * 4;
  float* u   = (float*)w;        w += Dd * 4;
  float* v   = (float*)w;        w += Dd * 4;
  float* cpt = (float*)w;        w += 64;
  int*   sel = (int*)w;          w += (size_t)Mm * 4;
  int*   counts = (int*)w;       w += 64;

  float* p_out = out + (size_t)Mm * Dd;
  float* b_out = p_out + Mm;

  // prep: G, u, v, c (independent of X)
  gemm_g<<<dim3(16, 16), 256, 0, stream>>>(Wq, Wk, G);
  uv_pass<<<dim3(4, 2), 256, 0, stream>>>(Wq, Wk, bq, bk, u, v);
  c_pass<<<1, 64, 0, stream>>>(bq, bk, cpt);
  // splits
  split_x<<<Mm / 4, 256, 0, stream>>>(x, u, v, Xh, Xl, a_u, a_v);
  split_kernel<<<(Dd * Dd / 4) / 256, 256, 0, stream>>>(G, Gh, Gl, Dd * Dd / 4);
  split_kernel<<<(Dd * Dd / 4) / 256, 256, 0, stream>>>(Wq, Wh, Wl, Dd * Dd / 4);
  split_kernel<<<(Dd * Dd / 4) / 256, 256, 0, stream>>>(Wk, Wh + (size_t)Dd * Dd, Wl + (size_t)Dd * Dd, Dd * Dd / 4);
  // GEMMs
  gemm_y<<<dim3(Dd / 128, Mm / 128), 256, 0, stream>>>(Xh, Xl, Gh, Gl, Y);
  gemm_norm<<<dim3(2 * Dd / 128, Mm / 128), 256, 0, stream>>>(Xh, Wh, bq, bk, partials);
  // epilogue chain
  cos_pass<<<Mm / 4, 256, 0, stream>>>(x, Y, partials, a_u, a_v, cpt, p_out, b_out);
  scan_flags<<<Bb, 256, 0, stream>>>(b_out, sel, counts);
  write_out<<<Mm, 256, 0, stream>>>(x, sel, counts, out);
}

// Round 3
// 893.228 us; speedup vs baseline: 2.3041x; 2.3041x over previous
//
#include <hip/hip_runtime.h>
#include <stdint.h>

#define Bb 8
#define Ss 4096
#define Dd 1024
#define Mm (Bb*Ss)      // 32768 rows
#define Kk 1024

typedef _Float16 half8 __attribute__((ext_vector_type(8)));
typedef _Float16 half4v __attribute__((ext_vector_type(4)));
typedef float f32x4 __attribute__((ext_vector_type(4)));

#define LO_SCALE 2048.0f
#define INV_LO_SCALE (1.0f/2048.0f)

__device__ __forceinline__ void gld_lds16(const void* g, void* l) {
  __builtin_amdgcn_global_load_lds(
      (const __attribute__((address_space(1))) unsigned int*)g,
      (__attribute__((address_space(3))) unsigned int*)l, 16, 0, 0);
}

// ---------------- elementwise fp32 -> f16 hi/lo split (lo pre-scaled) --------
__global__ void split_kernel(const float* __restrict__ src,
                             _Float16* __restrict__ hi,
                             _Float16* __restrict__ lo, int n4) {
  int i = blockIdx.x * 256 + threadIdx.x;
  if (i >= n4) return;
  float4 v = ((const float4*)src)[i];
  _Float16 h0 = (_Float16)v.x, h1 = (_Float16)v.y, h2 = (_Float16)v.z, h3 = (_Float16)v.w;
  _Float16 l0 = (_Float16)((v.x - (float)h0) * LO_SCALE);
  _Float16 l1 = (_Float16)((v.y - (float)h1) * LO_SCALE);
  _Float16 l2 = (_Float16)((v.z - (float)h2) * LO_SCALE);
  _Float16 l3 = (_Float16)((v.w - (float)h3) * LO_SCALE);
  ((half4v*)hi)[i] = (half4v){h0, h1, h2, h3};
  ((half4v*)lo)[i] = (half4v){l0, l1, l2, l3};
}

// ---------------- X split (wave/row) + a_u = u.x, a_v = v.x ------------------
__global__ void split_x(const float* __restrict__ X, const float* __restrict__ u,
                        const float* __restrict__ v,
                        _Float16* __restrict__ Xh, _Float16* __restrict__ Xl,
                        float* __restrict__ a_u, float* __restrict__ a_v) {
  const int s = blockIdx.x * 4 + (threadIdx.x >> 6);
  const int lane = threadIdx.x & 63;
  float au = 0.f, av = 0.f;
#pragma unroll
  for (int c = 0; c < 4; ++c) {
    const int e = c * 256 + lane * 4;
    float4 xv = *(const float4*)&X[(size_t)s * Dd + e];
    float4 uv = *(const float4*)&u[e];
    float4 vv = *(const float4*)&v[e];
    _Float16 h0 = (_Float16)xv.x, h1 = (_Float16)xv.y, h2 = (_Float16)xv.z, h3 = (_Float16)xv.w;
    _Float16 l0 = (_Float16)((xv.x - (float)h0) * LO_SCALE);
    _Float16 l1 = (_Float16)((xv.y - (float)h1) * LO_SCALE);
    _Float16 l2 = (_Float16)((xv.z - (float)h2) * LO_SCALE);
    _Float16 l3 = (_Float16)((xv.w - (float)h3) * LO_SCALE);
    *(half4v*)&Xh[(size_t)s * Dd + e] = (half4v){h0, h1, h2, h3};
    *(half4v*)&Xl[(size_t)s * Dd + e] = (half4v){l0, l1, l2, l3};
    au += uv.x * xv.x + uv.y * xv.y + uv.z * xv.z + uv.w * xv.w;
    av += vv.x * xv.x + vv.y * xv.y + vv.z * xv.z + vv.w * xv.w;
  }
#pragma unroll
  for (int off = 32; off > 0; off >>= 1) {
    au += __shfl_xor(au, off);
    av += __shfl_xor(av, off);
  }
  if (lane == 0) { a_u[s] = au; a_v[s] = av; }
}

// ---------------- G = Wq^T * Wk (fp32 vector GEMM, 64x64 tiles) --------------
__global__ __launch_bounds__(256)
void gemm_g(const float* __restrict__ Wq, const float* __restrict__ Wk,
            float* __restrict__ G) {
  __shared__ float As[16][64];
  __shared__ float Bs[16][64];
  const int t = threadIdx.x;
  const int m0 = blockIdx.y * 64, n0 = blockIdx.x * 64;
  float acc[4][4];
#pragma unroll
  for (int a = 0; a < 4; ++a)
#pragma unroll
    for (int b = 0; b < 4; ++b) acc[a][b] = 0.f;
  for (int kc = 0; kc < 64; ++kc) {
    const int k0 = kc * 16;
#pragma unroll
    for (int l = 0; l < 4; ++l) {
      const int idx = l * 256 + t;
      const int kk = idx >> 6, mm = idx & 63;
      As[kk][mm] = Wq[(size_t)(k0 + kk) * Dd + m0 + mm];
      Bs[kk][mm] = Wk[(size_t)(k0 + kk) * Dd + n0 + mm];
    }
    __syncthreads();
    const int tm = (t & 15) * 4, tn = (t >> 4) * 4;
#pragma unroll
    for (int k = 0; k < 16; ++k) {
      float4 a4 = *(const float4*)&As[k][tm];
      float4 b4 = *(const float4*)&Bs[k][tn];
      const float aa[4] = {a4.x, a4.y, a4.z, a4.w};
      const float bb[4] = {b4.x, b4.y, b4.z, b4.w};
#pragma unroll
      for (int a = 0; a < 4; ++a)
#pragma unroll
        for (int b = 0; b < 4; ++b) acc[a][b] += aa[a] * bb[b];
    }
    __syncthreads();
  }
  const int tm = (t & 15) * 4, tn = (t >> 4) * 4;
#pragma unroll
  for (int a = 0; a < 4; ++a)
#pragma unroll
    for (int b = 0; b < 4; ++b)
      G[(size_t)(m0 + tm + a) * Dd + n0 + tn + b] = acc[a][b];
}

// ---------------- u[d] = sum_e bq[e] Wk[e,d]; v[d] = sum_e bk[e] Wq[e,d] -----
__global__ void uv_pass(const float* __restrict__ Wq, const float* __restrict__ Wk,
                        const float* __restrict__ bq, const float* __restrict__ bk,
                        float* __restrict__ u, float* __restrict__ v) {
  const int d = blockIdx.x * 256 + threadIdx.x;
  const int which = blockIdx.y;  // 0 -> u, 1 -> v
  const float* W = which ? Wq : Wk;
  const float* bb = which ? bk : bq;
  float acc = 0.f;
#pragma unroll 4
  for (int e = 0; e < Dd; ++e) acc += bb[e] * W[(size_t)e * Dd + d];
  if (which) v[d] = acc; else u[d] = acc;
}

__global__ void c_pass(const float* __restrict__ bq, const float* __restrict__ bk,
                       float* __restrict__ c) {
  const int lane = threadIdx.x;
  float a = 0.f;
#pragma unroll
  for (int i = 0; i < 16; ++i) a += bq[lane * 16 + i] * bk[lane * 16 + i];
#pragma unroll
  for (int off = 32; off > 0; off >>= 1) a += __shfl_xor(a, off);
  if (lane == 0) *c = a;
}

// ---------------- precise split GEMM: Y = X * G^T  (N=1024) ------------------
// NOTE: (256,2) launch bounds — accH+accX alone are 128 unified regs/thread;
// (256,4) forces a <=128-reg budget and the compiler spills the accumulators
// to scratch inside the K-loop (round 2: WRITE_SIZE 3.4 GB, MfmaUtil 6%).
__global__ __launch_bounds__(256, 2)
void gemm_y(const _Float16* __restrict__ Ah, const _Float16* __restrict__ Al,
            const _Float16* __restrict__ Bh, const _Float16* __restrict__ Bl,
            float* __restrict__ Y) {
  __shared__ __align__(16) _Float16 AsH[128 * 32];
  __shared__ __align__(16) _Float16 AsL[128 * 32];
  __shared__ __align__(16) _Float16 BsH[128 * 32];
  __shared__ __align__(16) _Float16 BsL[128 * 32];
  const int tid = threadIdx.x;
  const int wave = tid >> 6, lane = tid & 63;
  const int m0 = blockIdx.y * 128, n0 = blockIdx.x * 128;
  const int wm = (wave >> 1) * 64, wn = (wave & 1) * 64;

  f32x4 accH[4][4], accX[4][4];
#pragma unroll
  for (int i = 0; i < 4; ++i)
#pragma unroll
    for (int j = 0; j < 4; ++j) {
      accH[i][j] = (f32x4){0.f, 0.f, 0.f, 0.f};
      accX[i][j] = (f32x4){0.f, 0.f, 0.f, 0.f};
    }
  const int srow = lane >> 2, c8 = lane & 3;

  for (int kt = 0; kt < Kk / 32; ++kt) {
    const int k0 = kt * 32;
#pragma unroll
    for (int it = 0; it < 2; ++it) {
      const int R = wave * 32 + it * 16 + srow;
      const int sg = c8 ^ ((R >> 2) & 3);
      const int ldsoff = (wave * 32 + it * 16) * 32;
      const size_t ga = (size_t)(m0 + R) * Kk + k0 + sg * 8;
      const size_t gb = (size_t)(n0 + R) * Kk + k0 + sg * 8;
      gld_lds16(Ah + ga, &AsH[ldsoff]);
      gld_lds16(Al + ga, &AsL[ldsoff]);
      gld_lds16(Bh + gb, &BsH[ldsoff]);
      gld_lds16(Bl + gb, &BsL[ldsoff]);
    }
    __syncthreads();
    const int fr = lane & 15, g = lane >> 4;
    half8 bh[4], bl[4];
#pragma unroll
    for (int j = 0; j < 4; ++j) {
      const int R = wn + 16 * j + fr;
      const int slot = g ^ ((R >> 2) & 3);
      bh[j] = *(const half8*)&BsH[R * 32 + slot * 8];
      bl[j] = *(const half8*)&BsL[R * 32 + slot * 8];
    }
#pragma unroll
    for (int i = 0; i < 4; ++i) {
      const int R = wm + 16 * i + fr;
      const int slot = g ^ ((R >> 2) & 3);
      half8 ah = *(const half8*)&AsH[R * 32 + slot * 8];
      half8 al = *(const half8*)&AsL[R * 32 + slot * 8];
#pragma unroll
      for (int j = 0; j < 4; ++j) {
        accH[i][j] = __builtin_amdgcn_mfma_f32_16x16x32_f16(ah, bh[j], accH[i][j], 0, 0, 0);
        accX[i][j] = __builtin_amdgcn_mfma_f32_16x16x32_f16(ah, bl[j], accX[i][j], 0, 0, 0);
        accX[i][j] = __builtin_amdgcn_mfma_f32_16x16x32_f16(al, bh[j], accX[i][j], 0, 0, 0);
      }
    }
    __syncthreads();
  }
  const int quad = lane >> 4;
#pragma unroll
  for (int j = 0; j < 4; ++j) {
    const int n = n0 + wn + 16 * j + (lane & 15);
#pragma unroll
    for (int i = 0; i < 4; ++i) {
      const int row0 = m0 + wm + 16 * i + quad * 4;
#pragma unroll
      for (int r = 0; r < 4; ++r)
        Y[(size_t)(row0 + r) * Dd + n] = accH[i][j][r] + accX[i][j][r] * INV_LO_SCALE;
    }
  }
}

// ---------------- single-pass hh GEMM for norms (N=2048, no QK write) --------
__global__ __launch_bounds__(256, 2)
void gemm_norm(const _Float16* __restrict__ Ah, const _Float16* __restrict__ Bh,
               const float* __restrict__ bq, const float* __restrict__ bk,
               float* __restrict__ partials) {
  __shared__ __align__(16) _Float16 AsH[128 * 32];
  __shared__ __align__(16) _Float16 BsH[128 * 32];
  const int tid = threadIdx.x;
  const int wave = tid >> 6, lane = tid & 63;
  const int m0 = blockIdx.y * 128, n0 = blockIdx.x * 128;
  const int wm = (wave >> 1) * 64, wn = (wave & 1) * 64;

  f32x4 acc[4][4];
#pragma unroll
  for (int i = 0; i < 4; ++i)
#pragma unroll
    for (int j = 0; j < 4; ++j) acc[i][j] = (f32x4){0.f, 0.f, 0.f, 0.f};

  const int srow = lane >> 2, c8 = lane & 3;
  for (int kt = 0; kt < Kk / 32; ++kt) {
    const int k0 = kt * 32;
#pragma unroll
    for (int it = 0; it < 2; ++it) {
      const int R = wave * 32 + it * 16 + srow;
      const int sg = c8 ^ ((R >> 2) & 3);
      const int ldsoff = (wave * 32 + it * 16) * 32;
      gld_lds16(Ah + (size_t)(m0 + R) * Kk + k0 + sg * 8, &AsH[ldsoff]);
      gld_lds16(Bh + (size_t)(n0 + R) * Kk + k0 + sg * 8, &BsH[ldsoff]);
    }
    __syncthreads();
    const int fr = lane & 15, g = lane >> 4;
    half8 bh[4];
#pragma unroll
    for (int j = 0; j < 4; ++j) {
      const int R = wn + 16 * j + fr;
      const int slot = g ^ ((R >> 2) & 3);
      bh[j] = *(const half8*)&BsH[R * 32 + slot * 8];
    }
#pragma unroll
    for (int i = 0; i < 4; ++i) {
      const int R = wm + 16 * i + fr;
      const int slot = g ^ ((R >> 2) & 3);
      half8 ah = *(const half8*)&AsH[R * 32 + slot * 8];
#pragma unroll
      for (int j = 0; j < 4; ++j)
        acc[i][j] = __builtin_amdgcn_mfma_f32_16x16x32_f16(ah, bh[j], acc[i][j], 0, 0, 0);
    }
    __syncthreads();
  }
  // epilogue: per-row sum of (acc+bias)^2 over this wave's 64 cols
  const int quad = lane >> 4;
  float bias_j[4];
#pragma unroll
  for (int j = 0; j < 4; ++j) {
    const int n = n0 + wn + 16 * j + (lane & 15);
    bias_j[j] = (n < Dd) ? bq[n] : bk[n - Dd];
  }
  const int slot = blockIdx.x * 2 + (wave & 1);
#pragma unroll
  for (int i = 0; i < 4; ++i) {
#pragma unroll
    for (int r = 0; r < 4; ++r) {
      float vsum = 0.f;
#pragma unroll
      for (int j = 0; j < 4; ++j) {
        float q = acc[i][j][r] + bias_j[j];
        vsum += q * q;
      }
      vsum += __shfl_xor(vsum, 1);
      vsum += __shfl_xor(vsum, 2);
      vsum += __shfl_xor(vsum, 4);
      vsum += __shfl_xor(vsum, 8);
      if ((lane & 15) == 0)
        partials[(size_t)slot * Mm + (m0 + wm + 16 * i + quad * 4 + r)] = vsum;
    }
  }
}

// ---------------- cos / p / b (wave per row) ---------------------------------
__global__ void cos_pass(const float* __restrict__ X, const float* __restrict__ Y,
                         const float* __restrict__ P, const float* __restrict__ a_u,
                         const float* __restrict__ a_v, const float* __restrict__ cptr,
                         float* __restrict__ p_out, float* __restrict__ b_out) {
  const int s = blockIdx.x * 4 + (threadIdx.x >> 6);
  const int lane = threadIdx.x & 63;
  if ((s & (Ss - 1)) == 0) {
    if (lane == 0) { p_out[s] = 1.0f; b_out[s] = 1.0f; }
    return;
  }
  const float* xs = X + (size_t)s * Dd;
  const float* ym = Y + (size_t)(s - 1) * Dd;
  float d = 0.f;
#pragma unroll
  for (int c = 0; c < 4; ++c) {
    const int e = c * 256 + lane * 4;
    float4 xv = *(const float4*)&xs[e];
    float4 yv = *(const float4*)&ym[e];
    d += xv.x * yv.x + xv.y * yv.y + xv.z * yv.z + xv.w * yv.w;
  }
#pragma unroll
  for (int off = 32; off > 0; off >>= 1) d += __shfl_xor(d, off);

  float pn = 0.f;
  if (lane < 32) pn = P[(size_t)lane * Mm + ((lane < 16) ? s : (s - 1))];
  pn += __shfl_xor(pn, 1);
  pn += __shfl_xor(pn, 2);
  pn += __shfl_xor(pn, 4);
  pn += __shfl_xor(pn, 8);
  float nk2 = __shfl(pn, 16);
  if (lane == 0) {
    float nq2 = pn;
    float dot = d + a_u[s - 1] + a_v[s] + *cptr;
    float denom = fmaxf(sqrtf(nq2), 1e-8f) * fmaxf(sqrtf(nk2), 1e-8f);
    float cs = dot / denom;
    float p = 0.5f * (1.0f - cs);
    p_out[s] = p;
    b_out[s] = (p >= 0.5f) ? 1.0f : 0.0f;
  }
}

// ---------------- per-batch stable scan of flags -----------------------------
__global__ void scan_flags(const float* __restrict__ b_out,
                           int* __restrict__ sel, int* __restrict__ counts) {
  const int b = blockIdx.x;
  const int tid = threadIdx.x;
  const int lane = tid & 63;
  const int w = tid >> 6;
  __shared__ int wtot[4];
  int running = 0;
  for (int c = 0; c < Ss / 256; ++c) {
    const int i = c * 256 + tid;
    const bool f = b_out[b * Ss + i] != 0.0f;
    unsigned long long m = __ballot(f);
    int pre = __popcll(m & ((1ull << lane) - 1ull));
    if (lane == 0) wtot[w] = __popcll(m);
    __syncthreads();
    int woff = 0;
#pragma unroll
    for (int ww = 0; ww < 4; ++ww)
      if (ww < w) woff += wtot[ww];
    int tot = wtot[0] + wtot[1] + wtot[2] + wtot[3];
    if (f) sel[b * Ss + running + woff + pre] = i;
    running += tot;
    __syncthreads();
  }
  if (tid == 0) counts[b] = running;
}

// ---------------- gather selected rows / zero-fill ---------------------------
__global__ void write_out(const float* __restrict__ x, const int* __restrict__ sel,
                          const int* __restrict__ counts, float* __restrict__ out) {
  const int blk = blockIdx.x;
  const int b = blk >> 12;
  const int r = blk & (Ss - 1);
  const int tid = threadIdx.x;
  float4 v = {0.f, 0.f, 0.f, 0.f};
  if (r < counts[b]) {
    const int src = sel[b * Ss + r];
    v = *(const float4*)&x[((size_t)b * Ss + src) * Dd + tid * 4];
  }
  *(float4*)&out[(size_t)blk * Dd + tid * 4] = v;
}

extern "C" void kernel_launch(void* const* d_in, const int* in_sizes, int n_in,
                              void* d_out, int out_size, void* d_ws, size_t ws_size,
                              hipStream_t stream) {
  const float* x  = (const float*)d_in[0];
  const float* Wq = (const float*)d_in[1];
  const float* bq = (const float*)d_in[2];
  const float* Wk = (const float*)d_in[3];
  const float* bk = (const float*)d_in[4];
  float* out = (float*)d_out;

  uint8_t* w = (uint8_t*)d_ws;
  _Float16* Xh = (_Float16*)w;   w += (size_t)Mm * Kk * 2;   // 64 MB
  _Float16* Xl = (_Float16*)w;   w += (size_t)Mm * Kk * 2;   // 64 MB
  float*    Y  = (float*)w;      w += (size_t)Mm * Dd * 4;   // 128 MB
  float*    G  = (float*)w;      w += (size_t)Dd * Dd * 4;   // 4 MB
  _Float16* Gh = (_Float16*)w;   w += (size_t)Dd * Dd * 2;   // 2 MB
  _Float16* Gl = (_Float16*)w;   w += (size_t)Dd * Dd * 2;   // 2 MB
  _Float16* Wh = (_Float16*)w;   w += (size_t)2 * Dd * Dd * 2; // 4 MB
  _Float16* Wl = (_Float16*)w;   w += (size_t)2 * Dd * Dd * 2; // 4 MB
  float* partials = (float*)w;   w += (size_t)32 * Mm * 4;   // 4 MB
  float* a_u = (float*)w;        w += (size_t)Mm * 4;
  float* a_v = (float*)w;        w += (size_t)Mm * 4;
  float* u   = (float*)w;        w += Dd * 4;
  float* v   = (float*)w;        w += Dd * 4;
  float* cpt = (float*)w;        w += 64;
  int*   sel = (int*)w;          w += (size_t)Mm * 4;
  int*   counts = (int*)w;       w += 64;

  float* p_out = out + (size_t)Mm * Dd;
  float* b_out = p_out + Mm;

  // prep: G, u, v, c (independent of X)
  gemm_g<<<dim3(16, 16), 256, 0, stream>>>(Wq, Wk, G);
  uv_pass<<<dim3(4, 2), 256, 0, stream>>>(Wq, Wk, bq, bk, u, v);
  c_pass<<<1, 64, 0, stream>>>(bq, bk, cpt);
  // splits
  split_x<<<Mm / 4, 256, 0, stream>>>(x, u, v, Xh, Xl, a_u, a_v);
  split_kernel<<<(Dd * Dd / 4) / 256, 256, 0, stream>>>(G, Gh, Gl, Dd * Dd / 4);
  split_kernel<<<(Dd * Dd / 4) / 256, 256, 0, stream>>>(Wq, Wh, Wl, Dd * Dd / 4);
  split_kernel<<<(Dd * Dd / 4) / 256, 256, 0, stream>>>(Wk, Wh + (size_t)Dd * Dd, Wl + (size_t)Dd * Dd, Dd * Dd / 4);
  // GEMMs
  gemm_y<<<dim3(Dd / 128, Mm / 128), 256, 0, stream>>>(Xh, Xl, Gh, Gl, Y);
  gemm_norm<<<dim3(2 * Dd / 128, Mm / 128), 256, 0, stream>>>(Xh, Wh, bq, bk, partials);
  // epilogue chain
  cos_pass<<<Mm / 4, 256, 0, stream>>>(x, Y, partials, a_u, a_v, cpt, p_out, b_out);
  scan_flags<<<Bb, 256, 0, stream>>>(b_out, sel, counts);
  write_out<<<Mm, 256, 0, stream>>>(x, sel, counts, out);
}